// Round 10
// baseline (58.125 us; speedup 1.0000x reference)
//
#include <hip/hip_runtime.h>

#define N_IN   4096
#define N_OUT  4082      // 4096 - 15 + 1
#define KS     15
#define TM     128       // output rows per block (4 chunks x 32)
#define TN     256       // output cols per block
#define CH     32        // output rows per chunk (2 bands x 16, p-interleaved)
#define NCH    4         // chunks per block
#define PR     142       // patch rows needed (TM + KS - 1)
#define PC     272       // patch cols staged (TN + 16)
#define C4R    68        // float4 chunks per patch row (PC/4)
#define RING   96        // ring rows; per-chunk live span 78 < 96 -> alias-free
#define PITEMS (46 * C4R)          // prologue items (rows [0,46)) = 3128
#define CITEMS (CH * C4R)          // per-chunk staging items = 2176
#define RMOD(r) ((r) >= RING ? (r) - RING : (r))   // rows < 2*RING always

// LDS: ring only, 96*272*2 = 52,224 B.
// REGISTER LEDGER: R9 measured 52 VGPR with bfrag in LDS. R10 moves bfrag
// (15 x bf16x8 = 60 regs) back to VGPRs: predicted ~108 < 128 cap of
// __launch_bounds__(512,4). Anchored on measured 52, unlike R7/R8 guesses.
// Spill gauge: WRITE_SIZE - 66.6 MB must stay ~0; fallback = hybrid B split.
// Bank: ring pitch 272 bf16 = 136 words == 8 mod 32 -> b128 conflict floor
// (R6/R9: 0 measured conflicts). Linear, no swizzle.

typedef __attribute__((ext_vector_type(8))) short bf16x8;
typedef __attribute__((ext_vector_type(4))) float f32x4;

__device__ inline unsigned short f2bf(float f) {   // round-to-nearest-even
    unsigned u = __builtin_bit_cast(unsigned, f);
    u += 0x7FFFu + ((u >> 16) & 1u);
    return (unsigned short)(u >> 16);
}
__device__ inline ushort4 f2bf4(float4 v) {
    ushort4 b; b.x = f2bf(v.x); b.y = f2bf(v.y); b.z = f2bf(v.z); b.w = f2bf(v.w);
    return b;
}

// load one staging item (patch row = base + it/C4R) into v, zero-padded
#define ISSUE_ITEM(base, it, v) {                                         \
    const int _row = (base) + (it) / C4R;                                 \
    const int _c4  = (it) % C4R;                                          \
    const int _gr  = r0 + _row;                                           \
    const int _gc  = c0 + _c4 * 4;                                        \
    if (_row < PR && _gr < N_IN && _gc < N_IN)                            \
        v = *reinterpret_cast<const float4*>(&x[_gr * N_IN + _gc]);       \
}
// convert + write item into its ring slot
#define COMMIT_ITEM(base, it, v) {                                        \
    const int _row = (base) + (it) / C4R;                                 \
    if (_row < PR) {                                                      \
        const int _ring = RMOD(_row);                                     \
        const int _c4   = (it) % C4R;                                     \
        *reinterpret_cast<ushort4*>(&xs[_ring * PC + _c4 * 4]) = f2bf4(v);\
    }                                                                     \
}

__global__ __launch_bounds__(512, 4) void Conv2DScratch_82025285419642_kernel(
    const float* __restrict__ x, const float* __restrict__ w,
    const float* __restrict__ bias, float* __restrict__ out)
{
    __shared__ unsigned short xs[RING * PC];   // 52,224 B

    const int tid  = threadIdx.x;
    const int lane = tid & 63;
    const int wv   = tid >> 6;            // 0..7 : wave owns cols [32wv, 32wv+32)
    const int m    = lane & 15;           // A row within band / D col
    const int g    = lane >> 4;           // k-group / D row group

    // bijective XCD-chunked block swizzle (512 blocks, 8 XCDs, 64 each)
    const int bid = blockIdx.x;
    const int s   = ((bid & 7) << 6) | (bid >> 3);
    const int c0  = (s & 15) * TN;        // output col base
    const int r0  = (s >> 4) * TM;        // output row base

    // ---- prologue: stage rows [0,46); build reg B-frags while loads fly ----
    float4 p0 = make_float4(0.f,0.f,0.f,0.f), p1 = p0, p2 = p0;
    ISSUE_ITEM(0, tid,        p0);
    ISSUE_ITEM(0, tid +  512, p1);
    ISSUE_ITEM(0, tid + 1024, p2);

    // B[(p,q)][n] = w[p][q-n]; lane: n = m, q = g*8+e  (verified R2)
    bf16x8 bfrag[KS];
    #pragma unroll
    for (int p = 0; p < KS; ++p) {
        #pragma unroll
        for (int e = 0; e < 8; ++e) {
            const int idx = g * 8 + e - m;               // filter col
            const float vv = (idx >= 0 && idx < KS) ? w[p * KS + idx] : 0.f;
            bfrag[p][e] = (short)f2bf(vv);
        }
    }
    const float b0 = bias[0];

    COMMIT_ITEM(0, tid,        p0);
    COMMIT_ITEM(0, tid +  512, p1);
    COMMIT_ITEM(0, tid + 1024, p2);

    p0 = make_float4(0.f,0.f,0.f,0.f); p1 = p0; p2 = p0;
    ISSUE_ITEM(0, tid + 1536, p0);
    ISSUE_ITEM(0, tid + 2048, p1);
    ISSUE_ITEM(0, tid + 2560, p2);       // 2560+511 = 3071 < 3128: no guard
    COMMIT_ITEM(0, tid + 1536, p0);
    COMMIT_ITEM(0, tid + 2048, p1);
    COMMIT_ITEM(0, tid + 2560, p2);
    if (tid < PITEMS - 3072) {           // 56-item tail
        float4 pt = make_float4(0.f,0.f,0.f,0.f);
        ISSUE_ITEM(0, tid + 3072, pt);
        COMMIT_ITEM(0, tid + 3072, pt);
    }
    __syncthreads();

    const int colbase = wv * 32 + g * 8;   // A-frag col (bf16) within ring row

    // one p-step: 4 A-reads + 4 independent MFMAs (B from registers)
    #define PSTEP(p) {                                                    \
        const unsigned short* a0p = &xs[RMOD(rb0 + (p)) * PC + colbase];  \
        const unsigned short* a1p = &xs[RMOD(rb1 + (p)) * PC + colbase];  \
        acc00 = __builtin_amdgcn_mfma_f32_16x16x32_bf16(                  \
            *reinterpret_cast<const bf16x8*>(a0p),      bfrag[p], acc00, 0,0,0);\
        acc01 = __builtin_amdgcn_mfma_f32_16x16x32_bf16(                  \
            *reinterpret_cast<const bf16x8*>(a0p + 16), bfrag[p], acc01, 0,0,0);\
        acc10 = __builtin_amdgcn_mfma_f32_16x16x32_bf16(                  \
            *reinterpret_cast<const bf16x8*>(a1p),      bfrag[p], acc10, 0,0,0);\
        acc11 = __builtin_amdgcn_mfma_f32_16x16x32_bf16(                  \
            *reinterpret_cast<const bf16x8*>(a1p + 16), bfrag[p], acc11, 0,0,0);\
    }

    #define STORE_BAND(rbase, a0, a1) {                                   \
        const int _oc  = c0 + wv * 32 + m;                                \
        const int _or0 = r0 + (rbase) + g * 4;                            \
        _Pragma("unroll")                                                 \
        for (int r = 0; r < 4; ++r) {                                     \
            const int _or = _or0 + r;                                     \
            if (_or < N_OUT) {                                            \
                if (_oc < N_OUT)      out[_or * N_OUT + _oc]      = a0[r] + b0; \
                if (_oc + 16 < N_OUT) out[_or * N_OUT + _oc + 16] = a1[r] + b0; \
            }                                                             \
        }                                                                 \
    }

    // ---- ring loop: compute out rows [32c,32c+32), stage patch [32c+46,32c+78) ----
    for (int c = 0; c < NCH; ++c) {
        const int srow = 46 + c * CH;      // staging base row this chunk
        const int rb0  = c * CH + m;       // band-0 patch row for p=0
        const int rb1  = rb0 + 16;         // band-1

        float4 s0 = make_float4(0.f,0.f,0.f,0.f), s1 = s0, s2 = s0;
        ISSUE_ITEM(srow, tid,        s0);
        ISSUE_ITEM(srow, tid +  512, s1);
        ISSUE_ITEM(srow, tid + 1024, s2);

        f32x4 acc00 = {0.f,0.f,0.f,0.f}, acc01 = acc00, acc10 = acc00, acc11 = acc00;
        PSTEP(0) PSTEP(1) PSTEP(2) PSTEP(3) PSTEP(4) PSTEP(5) PSTEP(6) PSTEP(7)

        COMMIT_ITEM(srow, tid,        s0);
        COMMIT_ITEM(srow, tid +  512, s1);
        COMMIT_ITEM(srow, tid + 1024, s2);
        s0 = make_float4(0.f,0.f,0.f,0.f); s1 = s0;
        ISSUE_ITEM(srow, tid + 1536, s0);
        if (tid < CITEMS - 2048) ISSUE_ITEM(srow, tid + 2048, s1);   // 128 tail

        PSTEP(8) PSTEP(9) PSTEP(10) PSTEP(11) PSTEP(12) PSTEP(13) PSTEP(14)

        COMMIT_ITEM(srow, tid + 1536, s0);
        if (tid < CITEMS - 2048) COMMIT_ITEM(srow, tid + 2048, s1);

        STORE_BAND(c * CH,      acc00, acc01);
        STORE_BAND(c * CH + 16, acc10, acc11);

        __syncthreads();                   // staged rows visible for chunk c+1
    }
    #undef PSTEP
    #undef STORE_BAND
}

extern "C" void kernel_launch(void* const* d_in, const int* in_sizes, int n_in,
                              void* d_out, int out_size, void* d_ws, size_t ws_size,
                              hipStream_t stream) {
    const float* x    = (const float*)d_in[0];
    const float* w    = (const float*)d_in[1];
    const float* bias = (const float*)d_in[2];
    float* out        = (float*)d_out;

    dim3 block(512);
    dim3 grid(16 * 32);   // 512 blocks, swizzled in-kernel; 2/CU, all resident
    Conv2DScratch_82025285419642_kernel<<<grid, block, 0, stream>>>(x, w, bias, out);
}

// Round 11
// 35.435 us; speedup vs baseline: 1.6403x; 1.6403x over previous
//
#include <hip/hip_runtime.h>

#define N_IN   4096
#define N_OUT  4082      // 4096 - 15 + 1
#define KS     15
#define TM     128       // output rows per block (4 chunks x 32)
#define TN     256       // output cols per block
#define CH     32        // output rows per chunk (2 row-groups x 16)
#define NCH    4         // chunks per block
#define PR     142       // patch rows needed (TM + KS - 1)
#define PC     272       // patch cols staged (TN + 16)
#define PCB    (PC * 2)  // ring row pitch in bytes = 544
#define C4R    68        // float4 chunks per patch row (PC/4)
#define RING   96        // ring rows; per-chunk live span 78 < 96 -> alias-free
#define PITEMS (46 * C4R)          // prologue items (rows [0,46)) = 3128
#define CITEMS (CH * C4R)          // per-chunk staging items = 2176
#define RMOD(r) ((r) >= RING ? (r) - RING : (r))   // rows < 2*RING always
#define BTAB_U (16 * 64 * 8)       // B-table: 16 entries x 64 lanes x 8 bf16

// R11: shared-window pairing. k = 16p' + q' (p'=g>>1, q'=(g&1)*8+e — same
// physical k=8g+e mapping verified since R2). Pair P = filter rows {2P,2P+1}
// (row 15 zero-padded; A-row clamped to 14 so row 46 is never read -> same
// ring discipline as R9). Wave = 16 rows x 64 cols (4 tiles): per pair
// 5 A-reads (windows s=0..4, shared between adjacent tiles) + 2 B-reads
// feed 8 MFMAs -> 0.875 LDS reads/MFMA vs R9's 1.25 (-25% LDS traffic).
// LDS: ring 52,224 + B-table 16,384 = 68,608 B -> 2 blocks/CU.
// REGISTER LESSON (R4/5/7/8/10): B table stays in LDS. Spill gauge:
// WRITE_SIZE - 66.6 MB must be ~0.
// Bank: quad = (2*row + (g&1) + 2s) mod 8 -> exactly 8 lanes/quad (floor);
// ring wrap shifts rows by 96 -> 2*96 == 0 mod 8, pattern preserved.

typedef __attribute__((ext_vector_type(8))) short bf16x8;
typedef __attribute__((ext_vector_type(4))) float f32x4;

__device__ inline unsigned short f2bf(float f) {   // round-to-nearest-even
    unsigned u = __builtin_bit_cast(unsigned, f);
    u += 0x7FFFu + ((u >> 16) & 1u);
    return (unsigned short)(u >> 16);
}
__device__ inline ushort4 f2bf4(float4 v) {
    ushort4 b; b.x = f2bf(v.x); b.y = f2bf(v.y); b.z = f2bf(v.z); b.w = f2bf(v.w);
    return b;
}

// load one staging item (patch row = base + it/C4R) into v, zero-padded
#define ISSUE_ITEM(base, it, v) {                                         \
    const int _row = (base) + (it) / C4R;                                 \
    const int _c4  = (it) % C4R;                                          \
    const int _gr  = r0 + _row;                                           \
    const int _gc  = c0 + _c4 * 4;                                        \
    if (_row < PR && _gr < N_IN && _gc < N_IN)                            \
        v = *reinterpret_cast<const float4*>(&x[_gr * N_IN + _gc]);       \
}
// convert + write item into its ring slot
#define COMMIT_ITEM(base, it, v) {                                        \
    const int _row = (base) + (it) / C4R;                                 \
    if (_row < PR) {                                                      \
        const int _ring = RMOD(_row);                                     \
        const int _c4   = (it) % C4R;                                     \
        *reinterpret_cast<ushort4*>(&xs[_ring * PC + _c4 * 4]) = f2bf4(v);\
    }                                                                     \
}

#define MF(a, b, c) __builtin_amdgcn_mfma_f32_16x16x32_bf16((a), (b), (c), 0, 0, 0)

__global__ __launch_bounds__(512, 4) void Conv2DScratch_82025285419642_kernel(
    const float* __restrict__ x, const float* __restrict__ w,
    const float* __restrict__ bias, float* __restrict__ out)
{
    __shared__ unsigned short xs[RING * PC + BTAB_U];   // ring + B table = 68,608 B

    const int tid  = threadIdx.x;
    const int lane = tid & 63;
    const int wv   = tid >> 6;
    const int m    = lane & 15;           // A row within band / D col
    const int g    = lane >> 4;           // k-group / D row group
    const int gp   = g >> 1;              // p' within pair
    const int g1   = g & 1;               // q' high/low 8
    const int wc   = wv & 3;              // col-group: cols [64wc, 64wc+64)
    const int wr   = wv >> 2;             // row-group: rows [32c+16wr, +16)

    // bijective XCD-chunked block swizzle (512 blocks, 8 XCDs, 64 each)
    const int bid = blockIdx.x;
    const int s   = ((bid & 7) << 6) | (bid >> 3);
    const int c0  = (s & 15) * TN;        // output col base
    const int r0  = (s >> 4) * TM;        // output row base

    // ---- prologue: stage rows [0,46); wave 0 builds B table while in flight ----
    float4 p0 = make_float4(0.f,0.f,0.f,0.f), p1 = p0, p2 = p0;
    ISSUE_ITEM(0, tid,        p0);
    ISSUE_ITEM(0, tid +  512, p1);
    ISSUE_ITEM(0, tid + 1024, p2);

    unsigned char* btb_w = (unsigned char*)&xs[RING * PC];
    if (wv == 0) {
        // entry (P,h): B[k=16p'+q'][n=m] = wpad[2P+p'][q' + 16h - n]
        #pragma unroll
        for (int P = 0; P < 8; ++P) {
            #pragma unroll
            for (int h = 0; h < 2; ++h) {
                bf16x8 f;
                #pragma unroll
                for (int e = 0; e < 8; ++e) {
                    const int prow = 2 * P + gp;
                    const int idx  = g1 * 8 + e + 16 * h - m;
                    const float vv = (prow < KS && idx >= 0 && idx < KS)
                                         ? w[prow * KS + idx] : 0.f;
                    f[e] = (short)f2bf(vv);
                }
                *reinterpret_cast<bf16x8*>(btb_w + (P * 2 + h) * 1024 + lane * 16) = f;
            }
        }
    }
    const float b0 = bias[0];

    COMMIT_ITEM(0, tid,        p0);
    COMMIT_ITEM(0, tid +  512, p1);
    COMMIT_ITEM(0, tid + 1024, p2);

    p0 = make_float4(0.f,0.f,0.f,0.f); p1 = p0; p2 = p0;
    ISSUE_ITEM(0, tid + 1536, p0);
    ISSUE_ITEM(0, tid + 2048, p1);
    ISSUE_ITEM(0, tid + 2560, p2);       // 2560+511 = 3071 < 3128: no guard
    COMMIT_ITEM(0, tid + 1536, p0);
    COMMIT_ITEM(0, tid + 2048, p1);
    COMMIT_ITEM(0, tid + 2560, p2);
    if (tid < PITEMS - 3072) {           // 56-item tail
        float4 pt = make_float4(0.f,0.f,0.f,0.f);
        ISSUE_ITEM(0, tid + 3072, pt);
        COMMIT_ITEM(0, tid + 3072, pt);
    }
    __syncthreads();

    const unsigned char* xsb = (const unsigned char*)xs;
    const unsigned char* btb = btb_w;
    const int cb0 = 128 * wc + 16 * g1;   // A-read byte offset within ring row

    // one pair-step: 5 shared A-windows + 2 B-frags -> 8 MFMAs
    #define PPAIR(ROW) {                                                  \
        const unsigned char* _ab = xsb + RMOD(ROW) * PCB + cb0;           \
        const bf16x8 a0 = *reinterpret_cast<const bf16x8*>(_ab +   0);    \
        const bf16x8 a1 = *reinterpret_cast<const bf16x8*>(_ab +  32);    \
        const bf16x8 a2 = *reinterpret_cast<const bf16x8*>(_ab +  64);    \
        const bf16x8 a3 = *reinterpret_cast<const bf16x8*>(_ab +  96);    \
        const bf16x8 a4 = *reinterpret_cast<const bf16x8*>(_ab + 128);    \
        const bf16x8 bl = *reinterpret_cast<const bf16x8*>(btb + _Pb * 2048 + lane * 16); \
        const bf16x8 bh = *reinterpret_cast<const bf16x8*>(btb + _Pb * 2048 + 1024 + lane * 16); \
        acc0 = MF(a0, bl, acc0); acc0 = MF(a1, bh, acc0);                 \
        acc1 = MF(a1, bl, acc1); acc1 = MF(a2, bh, acc1);                 \
        acc2 = MF(a2, bl, acc2); acc2 = MF(a3, bh, acc2);                 \
        acc3 = MF(a3, bl, acc3); acc3 = MF(a4, bh, acc3);                 \
    }

    // ---- ring loop: compute out rows [32c,32c+32), stage patch [32c+46,32c+78) ----
    for (int c = 0; c < NCH; ++c) {
        const int srow = 46 + c * CH;      // staging base row this chunk
        const int rbg  = c * CH + 16 * wr + m + gp;   // A row base (pairs 0-6)
        const int rb7  = c * CH + 16 * wr + m + 14;   // pair 7 (row 15 clamped)

        float4 s0 = make_float4(0.f,0.f,0.f,0.f), s1 = s0, s2 = s0;
        ISSUE_ITEM(srow, tid,        s0);
        ISSUE_ITEM(srow, tid +  512, s1);
        ISSUE_ITEM(srow, tid + 1024, s2);

        f32x4 acc0 = {0.f,0.f,0.f,0.f}, acc1 = acc0, acc2 = acc0, acc3 = acc0;
        { const int _Pb = 0; PPAIR(rbg +  0) }
        { const int _Pb = 1; PPAIR(rbg +  2) }
        { const int _Pb = 2; PPAIR(rbg +  4) }
        { const int _Pb = 3; PPAIR(rbg +  6) }

        COMMIT_ITEM(srow, tid,        s0);
        COMMIT_ITEM(srow, tid +  512, s1);
        COMMIT_ITEM(srow, tid + 1024, s2);
        s0 = make_float4(0.f,0.f,0.f,0.f); s1 = s0;
        ISSUE_ITEM(srow, tid + 1536, s0);
        if (tid < CITEMS - 2048) ISSUE_ITEM(srow, tid + 2048, s1);   // 128 tail

        { const int _Pb = 4; PPAIR(rbg +  8) }
        { const int _Pb = 5; PPAIR(rbg + 10) }
        { const int _Pb = 6; PPAIR(rbg + 12) }
        { const int _Pb = 7; PPAIR(rb7) }

        COMMIT_ITEM(srow, tid + 1536, s0);
        if (tid < CITEMS - 2048) COMMIT_ITEM(srow, tid + 2048, s1);

        // stores: tile t cols [64wc+16t, +16); D: col = m, row = g*4 + r
        const int ocb = c0 + 64 * wc + m;
        const int or0 = r0 + c * CH + 16 * wr + g * 4;
        #define STORE_TILE(t, a) {                                        \
            const int _oc = ocb + (t) * 16;                               \
            if (_oc < N_OUT) {                                            \
                _Pragma("unroll")                                         \
                for (int r = 0; r < 4; ++r) {                             \
                    if (or0 + r < N_OUT)                                  \
                        out[(or0 + r) * N_OUT + _oc] = a[r] + b0;         \
                }                                                         \
            }                                                             \
        }
        STORE_TILE(0, acc0) STORE_TILE(1, acc1)
        STORE_TILE(2, acc2) STORE_TILE(3, acc3)
        #undef STORE_TILE

        __syncthreads();                   // staged rows visible for chunk c+1
    }
    #undef PPAIR
}

extern "C" void kernel_launch(void* const* d_in, const int* in_sizes, int n_in,
                              void* d_out, int out_size, void* d_ws, size_t ws_size,
                              hipStream_t stream) {
    const float* x    = (const float*)d_in[0];
    const float* w    = (const float*)d_in[1];
    const float* bias = (const float*)d_in[2];
    float* out        = (float*)d_out;

    dim3 block(512);
    dim3 grid(16 * 32);   // 512 blocks, swizzled in-kernel; 2/CU, all resident
    Conv2DScratch_82025285419642_kernel<<<grid, block, 0, stream>>>(x, w, bias, out);
}